// Round 12
// baseline (20676.686 us; speedup 1.0000x reference)
//
#include <hip/hip_runtime.h>
#include <hip/hip_bf16.h>
#include <stdint.h>

#define HIDDEN 4096
#define INTER  14336
#define NSEL   4096

using short8 = __attribute__((ext_vector_type(8))) short;
using f32x4  = __attribute__((ext_vector_type(4))) float;

__device__ __forceinline__ uint16_t f2bf(float f) {
  uint32_t u = __float_as_uint(f);
  uint32_t r = (u + 0x7FFFu + ((u >> 16) & 1u)) >> 16;
  return (uint16_t)r;
}
__device__ __forceinline__ uint32_t pack2(float lo, float hi) {
  return (uint32_t)f2bf(lo) | ((uint32_t)f2bf(hi) << 16);
}

// ---- prep: gather x_sel->bf16 (blocks<NSEL) + cvt Wg,Wu fp32->bf16 ----
__global__ void prep(const float* __restrict__ x, const int* __restrict__ idx,
                     uint16_t* __restrict__ xs,
                     const float* __restrict__ Wg, uint16_t* __restrict__ w1,
                     const float* __restrict__ Wu, uint16_t* __restrict__ w2,
                     int ncvt) {
  const int b = blockIdx.x;
  const int t = threadIdx.x;
  if (b < NSEL) {
    const size_t s = (size_t)idx[b] * HIDDEN + (size_t)t * 16;
    const size_t d = (size_t)b * HIDDEN + (size_t)t * 16;
    const float4* sp = (const float4*)(x + s);
    float4 f0 = sp[0], f1 = sp[1], f2 = sp[2], f3 = sp[3];
    uint4 v0, v1;
    v0.x = pack2(f0.x, f0.y); v0.y = pack2(f0.z, f0.w);
    v0.z = pack2(f1.x, f1.y); v0.w = pack2(f1.z, f1.w);
    v1.x = pack2(f2.x, f2.y); v1.y = pack2(f2.z, f2.w);
    v1.z = pack2(f3.x, f3.y); v1.w = pack2(f3.z, f3.w);
    *(uint4*)(xs + d)     = v0;
    *(uint4*)(xs + d + 8) = v1;
    return;
  }
  int cb = b - NSEL;
  const float* src; uint16_t* dst;
  if (cb < ncvt) { src = Wg; dst = w1; }
  else           { src = Wu; dst = w2; cb -= ncvt; }
#pragma unroll
  for (int k = 0; k < 8; ++k) {
    const size_t i = (size_t)cb * 16384 + (size_t)k * 2048 + (size_t)t * 8;
    float4 a = *(const float4*)(src + i);
    float4 c = *(const float4*)(src + i + 4);
    uint4 v;
    v.x = pack2(a.x, a.y); v.y = pack2(a.z, a.w);
    v.z = pack2(c.x, c.y); v.w = pack2(c.z, c.w);
    *(uint4*)(dst + i) = v;
  }
}

__device__ __forceinline__ void gload16(const void* g, void* l) {
  __builtin_amdgcn_global_load_lds(
      (const __attribute__((address_space(1))) void*)g,
      (__attribute__((address_space(3))) void*)l, 16, 0, 0);
}

__device__ __forceinline__ float silu(float g) {
  return g / (1.f + __expf(-g));
}

// ============================================================================
// Fused NT GEMM — r11 structure with ring-2 / 2-blocks-per-CU.
// r11 audit: 1 block/CU (ring-4, 128KB) -> LDS ~70% busy, MFMA 52%, wall has
// ~30% uncovered stall. r4/r6 measured that 2 blocks/CU (cross-block TLP)
// covers per-tile drain stalls better than deeper prefetch. Ring-2 = 64KB
// -> 2 blocks x 16 waves = 32 waves/CU (max). VGPR 56 <= 64 so 8 waves/SIMD
// is legal; __launch_bounds__(1024,8) pins the allocator.
// Schedule (2-phase + TLP): per K32-tile {stage t+1 into other slot ->
// ds_read(t) -> setprio(1) 16 MFMA setprio(0) -> vmcnt(0) -> s_barrier}.
// The vmcnt(0) drain is covered by the co-resident block's compute.
// MODE 0 (gate+up): BM=256, BNout=128, TWO B panels (Wg,Wu 128 rows);
//   wave (s=w>>3, wm=w&3, wn=(w>>2)&1); epilogue g/u exchange via LDS
//   (bank-spread perm), h = silu(g)*u -> bf16 G. Tail blocks convert Wd.
// MODE 1 (down): BM=256, BN=256 single panel; out = acc*Wt[row], NT store.
// LDS swizzle (r2/r3/r6/r9/r11 measured-ZERO): line = 2 rows x 32 cols =
// 128B; slot16 = (((r&1)<<2)|lg) ^ ((r>>1)&7); pre-inverse-swizzled global
// source + LINEAR gload_lds dest (rule 21).
// T1 bijective XCD swizzle over the gemm sub-grid, bm-fastest.
// ============================================================================
template<int MODE>
__global__ __launch_bounds__(1024, 8) void gemm_f(
    const uint16_t* __restrict__ A,
    const uint16_t* __restrict__ B0,
    const uint16_t* __restrict__ B1,
    uint16_t* __restrict__ G,
    float* __restrict__ O,
    const float* __restrict__ Wt,
    int N, int K, int nGemm,
    const float* __restrict__ cvtIn, uint16_t* __restrict__ cvtOut)
{
  __shared__ __align__(16) uint16_t lds[2][16384];  // [slot][A 0..8191 | B 8192..16383]

  const int bid = (int)blockIdx.x;
  const int tid = (int)threadIdx.x;

  // ---- Wd-cvt tail (MODE 0 only): 65536 elems/block, 64/thread ----
  if (MODE == 0 && bid >= nGemm) {
    const int cb = bid - nGemm;
#pragma unroll
    for (int k = 0; k < 8; ++k) {
      const size_t i = (size_t)cb * 65536 + (size_t)k * 8192 + (size_t)tid * 8;
      float4 a = *(const float4*)(cvtIn + i);
      float4 c = *(const float4*)(cvtIn + i + 4);
      uint4 v;
      v.x = pack2(a.x, a.y); v.y = pack2(a.z, a.w);
      v.z = pack2(c.x, c.y); v.w = pack2(c.z, c.w);
      *(uint4*)(cvtOut + i) = v;
    }
    return;
  }

  const int lid = (bid & 7) * (nGemm >> 3) + (bid >> 3);
  const int bm = lid & 15, bn = lid >> 4;           // nbm = 16 always

  const int lane = tid & 63, w = tid >> 6;
  const int lr = lane & 15, lg = lane >> 4;

  int wm, wn, s;
  if constexpr (MODE == 0) { s = w >> 3; wm = w & 3; wn = (w >> 2) & 1; }
  else                     { s = 0;      wm = w & 3; wn = w >> 2;       }

  // ---- fragment read offsets (u16, slot-relative), proven-zero swizzle ----
  int offA[4], offB[4];
#pragma unroll
  for (int m = 0; m < 4; ++m) {
    const int r = wm * 64 + m * 16 + lr;
    offA[m] = (r >> 1) * 64 + (((((r & 1) << 2) | lg) ^ ((r >> 1) & 7)) * 8);
  }
  const int bBase = (MODE == 0) ? (8192 + s * 4096) : 8192;
#pragma unroll
  for (int n = 0; n < 4; ++n) {
    const int r = wn * 64 + n * 16 + lr;
    offB[n] = bBase + (r >> 1) * 64 + (((((r & 1) << 2) | lg) ^ ((r >> 1) & 7)) * 8);
  }

  // ---- staging (inverse-swizzled global source, linear gload_lds dest) ----
  const int suA   = (tid & 7) ^ ((tid >> 3) & 7);
  const int sRowA = 2 * (tid >> 3) + (suA >> 2);
  const int sColA = (suA & 3) * 8;
  const uint16_t* aSrc = A + (size_t)(bm * 256 + sRowA) * K + sColA;

  const int jB    = (MODE == 0) ? (tid & 511) : tid;
  const int suB   = (jB & 7) ^ ((jB >> 3) & 7);
  const int sRowB = 2 * (jB >> 3) + (suB >> 2);
  const int sColB = (suB & 3) * 8;
  const uint16_t* bSel = (MODE == 0) ? ((tid < 512) ? B0 : B1) : B0;
  const uint16_t* bSrc = bSel + (size_t)(bn * ((MODE == 0) ? 128 : 256) + sRowB) * K + sColB;
  const int bDst = (MODE == 0) ? (8192 + (tid >> 9) * 4096 + (tid & 511) * 8)
                               : (8192 + tid * 8);

#define STAGE(tt, sl) do { \
    gload16(aSrc + (size_t)(tt) * 32, &lds[sl][tid * 8]); \
    gload16(bSrc + (size_t)(tt) * 32, &lds[sl][bDst]); \
  } while (0)

  f32x4 acc[4][4];
#pragma unroll
  for (int m = 0; m < 4; ++m)
#pragma unroll
    for (int n = 0; n < 4; ++n)
#pragma unroll
      for (int j = 0; j < 4; ++j) acc[m][n][j] = 0.f;

  const int nk = K >> 5;

  // prologue: stage tile 0, drain, barrier
  STAGE(0, 0);
  asm volatile("s_waitcnt vmcnt(0)" ::: "memory");
  __builtin_amdgcn_s_barrier();

  for (int t = 0; t < nk; ++t) {
    const uint16_t* S = &lds[t & 1][0];

    if (t + 1 < nk) STAGE(t + 1, (t + 1) & 1);

    short8 av[4], bv[4];
#pragma unroll
    for (int m = 0; m < 4; ++m) av[m] = *(const short8*)&S[offA[m]];
#pragma unroll
    for (int n = 0; n < 4; ++n) bv[n] = *(const short8*)&S[offB[n]];

    __builtin_amdgcn_s_setprio(1);
#pragma unroll
    for (int m = 0; m < 4; ++m)
#pragma unroll
      for (int n = 0; n < 4; ++n)
        acc[m][n] = __builtin_amdgcn_mfma_f32_16x16x32_bf16(av[m], bv[n], acc[m][n], 0, 0, 0);
    __builtin_amdgcn_s_setprio(0);

    // certify tile t+1 (drain; covered by the co-resident block's compute)
    asm volatile("s_waitcnt vmcnt(0)" ::: "memory");
    __builtin_amdgcn_s_barrier();
  }
#undef STAGE

  // C/D layout: col = lane&15, row = (lane>>4)*4 + reg  [m89-verified]
  if constexpr (MODE == 1) {
    const int row0 = bm * 256 + wm * 64, col0 = bn * 256 + wn * 64;
#pragma unroll
    for (int m = 0; m < 4; ++m)
#pragma unroll
      for (int n = 0; n < 4; ++n) {
        const int c  = col0 + n * 16 + lr;
        const int rb = row0 + m * 16 + lg * 4;
#pragma unroll
        for (int j = 0; j < 4; ++j) {
          const int r = rb + j;
          __builtin_nontemporal_store(acc[m][n][j] * Wt[r], &O[(size_t)r * N + c]);
        }
      }
  } else {
    // g/u exchange via LDS; bank-spread perm (2-way max = free)
    float* X = (float*)&lds[0][0];   // 8 g-waves x 4KB = 32KB (loop-dead)
    const int xo = lr * 16 + ((lg ^ ((lr >> 1) & 3)) * 4);
    const int row0 = bm * 256 + wm * 64, col0 = bn * 128 + wn * 64;
#pragma unroll
    for (int m = 0; m < 4; ++m) {
      __builtin_amdgcn_s_barrier();          // prev phase's reads done
      if (s == 0) {
#pragma unroll
        for (int n = 0; n < 4; ++n)
          *(f32x4*)&X[w * 1024 + n * 256 + xo] = acc[m][n];
      }
      __builtin_amdgcn_s_barrier();          // writes visible
      if (s == 1) {
#pragma unroll
        for (int n = 0; n < 4; ++n) {
          const f32x4 g4 = *(const f32x4*)&X[(w - 8) * 1024 + n * 256 + xo];
          const int c  = col0 + n * 16 + lr;
          const int rb = row0 + m * 16 + lg * 4;
#pragma unroll
          for (int j = 0; j < 4; ++j)
            G[(size_t)(rb + j) * N + c] = f2bf(silu(g4[j]) * acc[m][n][j]);
        }
      }
    }
  }
}

extern "C" void kernel_launch(void* const* d_in, const int* in_sizes, int n_in,
                              void* d_out, int out_size, void* d_ws, size_t ws_size,
                              hipStream_t stream) {
  const float* x   = (const float*)d_in[0];
  const float* Wg  = (const float*)d_in[1];
  const float* Wu  = (const float*)d_in[2];
  const float* Wd  = (const float*)d_in[3];
  const int*   top = (const int*)d_in[4];
  const float* wt  = (const float*)d_in[5];
  float* out = (float*)d_out;

  const size_t NE_X = (size_t)NSEL * HIDDEN;
  const size_t NE_W = (size_t)INTER * HIDDEN;
  if (ws_size < (NE_X + 4 * NE_W) * sizeof(uint16_t)) return;

  uint16_t* xs = (uint16_t*)d_ws;
  uint16_t* w1 = xs + NE_X;    // Wg bf16
  uint16_t* w2 = w1 + NE_W;    // Wu bf16
  uint16_t* w3 = w2 + NE_W;    // Wd bf16
  uint16_t* gh = w3 + NE_W;    // h bf16 [NSEL][INTER]

  const int NCVT = (int)(NE_W / 16384);   // 3584 blocks per weight (prep)
  const int NCVT_GU = (int)(NE_W / 65536);// 896 tail blocks (inside GU)
  const int ngGU = 16 * (INTER / 128);    // 1792
  const int ngDN = 16 * (HIDDEN / 256);   // 256

  // gather + Wg,Wu cvts (Wd cvt rides inside the GU launch)
  prep<<<NSEL + 2 * NCVT, 256, 0, stream>>>(x, top, xs, Wg, w1, Wu, w2, NCVT);

  // fused gate+up: h = silu(x Wg^T) * (x Wu^T) -> gh; tail: Wd -> w3
  gemm_f<0><<<ngGU + NCVT_GU, 1024, 0, stream>>>(xs, w1, w2, gh, nullptr, nullptr,
                                                 INTER, HIDDEN, ngGU, Wd, w3);
  // down + routing weight: out = (h Wd^T) * weight[:,None]
  gemm_f<1><<<ngDN, 1024, 0, stream>>>(gh, w3, nullptr, nullptr, out, wt,
                                       HIDDEN, INTER, ngDN, nullptr, nullptr);
}

// Round 13
// 1386.144 us; speedup vs baseline: 14.9167x; 14.9167x over previous
//
#include <hip/hip_runtime.h>
#include <hip/hip_bf16.h>
#include <stdint.h>

#define HIDDEN 4096
#define INTER  14336
#define NSEL   4096

using short8 = __attribute__((ext_vector_type(8))) short;
using f32x4  = __attribute__((ext_vector_type(4))) float;

__device__ __forceinline__ uint16_t f2bf(float f) {
  uint32_t u = __float_as_uint(f);
  uint32_t r = (u + 0x7FFFu + ((u >> 16) & 1u)) >> 16;
  return (uint16_t)r;
}
__device__ __forceinline__ uint32_t pack2(float lo, float hi) {
  return (uint32_t)f2bf(lo) | ((uint32_t)f2bf(hi) << 16);
}

// ---- prep: gather x_sel->bf16 (blocks<NSEL) + cvt Wg,Wu fp32->bf16 ----
__global__ void prep(const float* __restrict__ x, const int* __restrict__ idx,
                     uint16_t* __restrict__ xs,
                     const float* __restrict__ Wg, uint16_t* __restrict__ w1,
                     const float* __restrict__ Wu, uint16_t* __restrict__ w2,
                     int ncvt) {
  const int b = blockIdx.x;
  const int t = threadIdx.x;
  if (b < NSEL) {
    const size_t s = (size_t)idx[b] * HIDDEN + (size_t)t * 16;
    const size_t d = (size_t)b * HIDDEN + (size_t)t * 16;
    const float4* sp = (const float4*)(x + s);
    float4 f0 = sp[0], f1 = sp[1], f2 = sp[2], f3 = sp[3];
    uint4 v0, v1;
    v0.x = pack2(f0.x, f0.y); v0.y = pack2(f0.z, f0.w);
    v0.z = pack2(f1.x, f1.y); v0.w = pack2(f1.z, f1.w);
    v1.x = pack2(f2.x, f2.y); v1.y = pack2(f2.z, f2.w);
    v1.z = pack2(f3.x, f3.y); v1.w = pack2(f3.z, f3.w);
    *(uint4*)(xs + d)     = v0;
    *(uint4*)(xs + d + 8) = v1;
    return;
  }
  int cb = b - NSEL;
  const float* src; uint16_t* dst;
  if (cb < ncvt) { src = Wg; dst = w1; }
  else           { src = Wu; dst = w2; cb -= ncvt; }
#pragma unroll
  for (int k = 0; k < 8; ++k) {
    const size_t i = (size_t)cb * 16384 + (size_t)k * 2048 + (size_t)t * 8;
    float4 a = *(const float4*)(src + i);
    float4 c = *(const float4*)(src + i + 4);
    uint4 v;
    v.x = pack2(a.x, a.y); v.y = pack2(a.z, a.w);
    v.z = pack2(c.x, c.y); v.w = pack2(c.z, c.w);
    *(uint4*)(dst + i) = v;
  }
}

__device__ __forceinline__ void gload16(const void* g, void* l) {
  __builtin_amdgcn_global_load_lds(
      (const __attribute__((address_space(1))) void*)g,
      (__attribute__((address_space(3))) void*)l, 16, 0, 0);
}

__device__ __forceinline__ float silu(float g) {
  return g / (1.f + __expf(-g));
}

// ============================================================================
// Fused NT GEMM — r11 structure (measured best: 1396 µs total). r12's
// __launch_bounds__(1024,8) is REVERTED: 8 waves/SIMD needs <=64 TOTAL regs
// (arch + acc unified on gfx950); acc alone is 64 -> compiler spilled acc to
// scratch (48 GB/dispatch HBM spill, 20.7 ms). 16 waves/CU is the hard
// ceiling for 64-reg-acc kernels; r11's 1 block x 16 waves is optimal.
// 1024 threads = 16 waves of 64x64 (acc 64 AGPR + ~56 arch VGPR). LDS slot
// = A 16KB + B 16KB; ring-4 = 128KB, 1 block/CU. Free-run schedule per
// K32-tile: {ds_read(t) -> stage t+3 -> setprio(1) 16 MFMA setprio(0) ->
// counted vmcnt certifying t+1 (t+2,t+3 in flight; never drains mid-loop)
// -> s_barrier}. ds_reads issued before STAGE (reads are critical-path).
// MODE 0 (gate+up): BM=256, BNout=128, TWO B panels (Wg,Wu 128 rows);
//   wave (s=w>>3, wm=w&3, wn=(w>>2)&1); epilogue g/u exchange via LDS
//   (bank-spread perm, conflict-free), h = silu(g)*u -> bf16 G.
//   Tail blocks (bid>=nGemm) convert Wd fp32->bf16 (consumed next launch).
// MODE 1 (down): BM=256, BN=256 single panel; out = acc*Wt[row], NT store.
// LDS swizzle (r2/r3/r6/r9/r11 measured-ZERO conflicts): line = 2 rows x 32
// cols = 128B; slot16 = (((r&1)<<2)|lg) ^ ((r>>1)&7); pre-inverse-swizzled
// global source + LINEAR gload_lds dest (rule 21).
// T1 bijective XCD swizzle over the gemm sub-grid, bm-fastest.
// ============================================================================
template<int MODE>
__global__ __launch_bounds__(1024, 4) void gemm_f(
    const uint16_t* __restrict__ A,
    const uint16_t* __restrict__ B0,
    const uint16_t* __restrict__ B1,
    uint16_t* __restrict__ G,
    float* __restrict__ O,
    const float* __restrict__ Wt,
    int N, int K, int nGemm,
    const float* __restrict__ cvtIn, uint16_t* __restrict__ cvtOut)
{
  __shared__ __align__(16) uint16_t lds[4][16384];  // [slot][A 0..8191 | B 8192..16383]

  const int bid = (int)blockIdx.x;
  const int tid = (int)threadIdx.x;

  // ---- Wd-cvt tail (MODE 0 only): 65536 elems/block, 64/thread ----
  if (MODE == 0 && bid >= nGemm) {
    const int cb = bid - nGemm;
#pragma unroll
    for (int k = 0; k < 8; ++k) {
      const size_t i = (size_t)cb * 65536 + (size_t)k * 8192 + (size_t)tid * 8;
      float4 a = *(const float4*)(cvtIn + i);
      float4 c = *(const float4*)(cvtIn + i + 4);
      uint4 v;
      v.x = pack2(a.x, a.y); v.y = pack2(a.z, a.w);
      v.z = pack2(c.x, c.y); v.w = pack2(c.z, c.w);
      *(uint4*)(cvtOut + i) = v;
    }
    return;
  }

  const int lid = (bid & 7) * (nGemm >> 3) + (bid >> 3);
  const int bm = lid & 15, bn = lid >> 4;           // nbm = 16 always

  const int lane = tid & 63, w = tid >> 6;
  const int lr = lane & 15, lg = lane >> 4;

  int wm, wn, s;
  if constexpr (MODE == 0) { s = w >> 3; wm = w & 3; wn = (w >> 2) & 1; }
  else                     { s = 0;      wm = w & 3; wn = w >> 2;       }

  // ---- fragment read offsets (u16, slot-relative), proven-zero swizzle ----
  int offA[4], offB[4];
#pragma unroll
  for (int m = 0; m < 4; ++m) {
    const int r = wm * 64 + m * 16 + lr;
    offA[m] = (r >> 1) * 64 + (((((r & 1) << 2) | lg) ^ ((r >> 1) & 7)) * 8);
  }
  const int bBase = (MODE == 0) ? (8192 + s * 4096) : 8192;
#pragma unroll
  for (int n = 0; n < 4; ++n) {
    const int r = wn * 64 + n * 16 + lr;
    offB[n] = bBase + (r >> 1) * 64 + (((((r & 1) << 2) | lg) ^ ((r >> 1) & 7)) * 8);
  }

  // ---- staging (inverse-swizzled global source, linear gload_lds dest) ----
  const int suA   = (tid & 7) ^ ((tid >> 3) & 7);
  const int sRowA = 2 * (tid >> 3) + (suA >> 2);
  const int sColA = (suA & 3) * 8;
  const uint16_t* aSrc = A + (size_t)(bm * 256 + sRowA) * K + sColA;

  const int jB    = (MODE == 0) ? (tid & 511) : tid;
  const int suB   = (jB & 7) ^ ((jB >> 3) & 7);
  const int sRowB = 2 * (jB >> 3) + (suB >> 2);
  const int sColB = (suB & 3) * 8;
  const uint16_t* bSel = (MODE == 0) ? ((tid < 512) ? B0 : B1) : B0;
  const uint16_t* bSrc = bSel + (size_t)(bn * ((MODE == 0) ? 128 : 256) + sRowB) * K + sColB;
  const int bDst = (MODE == 0) ? (8192 + (tid >> 9) * 4096 + (tid & 511) * 8)
                               : (8192 + tid * 8);

#define STAGE(tt, sl) do { \
    gload16(aSrc + (size_t)(tt) * 32, &lds[sl][tid * 8]); \
    gload16(bSrc + (size_t)(tt) * 32, &lds[sl][bDst]); \
  } while (0)

  f32x4 acc[4][4];
#pragma unroll
  for (int m = 0; m < 4; ++m)
#pragma unroll
    for (int n = 0; n < 4; ++n)
#pragma unroll
      for (int j = 0; j < 4; ++j) acc[m][n][j] = 0.f;

  const int nk = K >> 5;

  // prologue: stage tiles 0,1,2; certify tile 0 (4 loads stay in flight)
  STAGE(0, 0);
  STAGE(1, 1);
  STAGE(2, 2);
  asm volatile("s_waitcnt vmcnt(4)" ::: "memory");
  __builtin_amdgcn_s_barrier();

  for (int t = 0; t < nk; ++t) {
    const uint16_t* S = &lds[t & 3][0];

    // critical-path ds_reads first
    short8 av[4], bv[4];
#pragma unroll
    for (int m = 0; m < 4; ++m) av[m] = *(const short8*)&S[offA[m]];
#pragma unroll
    for (int n = 0; n < 4; ++n) bv[n] = *(const short8*)&S[offB[n]];

    if (t + 3 < nk) STAGE(t + 3, (t + 3) & 3);

    __builtin_amdgcn_s_setprio(1);
#pragma unroll
    for (int m = 0; m < 4; ++m)
#pragma unroll
      for (int n = 0; n < 4; ++n)
        acc[m][n] = __builtin_amdgcn_mfma_f32_16x16x32_bf16(av[m], bv[n], acc[m][n], 0, 0, 0);
    __builtin_amdgcn_s_setprio(0);

    // certify tile t+1; keep later prefetches in flight (never drain mid-loop)
    if      (t + 3 < nk) { asm volatile("s_waitcnt vmcnt(4)" ::: "memory"); }
    else if (t + 2 < nk) { asm volatile("s_waitcnt vmcnt(2)" ::: "memory"); }
    else                 { asm volatile("s_waitcnt vmcnt(0)" ::: "memory"); }
    __builtin_amdgcn_s_barrier();
  }
#undef STAGE

  // C/D layout: col = lane&15, row = (lane>>4)*4 + reg  [m89-verified]
  if constexpr (MODE == 1) {
    const int row0 = bm * 256 + wm * 64, col0 = bn * 256 + wn * 64;
#pragma unroll
    for (int m = 0; m < 4; ++m)
#pragma unroll
      for (int n = 0; n < 4; ++n) {
        const int c  = col0 + n * 16 + lr;
        const int rb = row0 + m * 16 + lg * 4;
#pragma unroll
        for (int j = 0; j < 4; ++j) {
          const int r = rb + j;
          __builtin_nontemporal_store(acc[m][n][j] * Wt[r], &O[(size_t)r * N + c]);
        }
      }
  } else {
    // g/u exchange via LDS; bank-spread perm (2-way max = free)
    float* X = (float*)&lds[0][0];   // 8 g-waves x 4KB = 32KB (loop-dead)
    const int xo = lr * 16 + ((lg ^ ((lr >> 1) & 3)) * 4);
    const int row0 = bm * 256 + wm * 64, col0 = bn * 128 + wn * 64;
#pragma unroll
    for (int m = 0; m < 4; ++m) {
      __builtin_amdgcn_s_barrier();          // prev phase's reads done
      if (s == 0) {
#pragma unroll
        for (int n = 0; n < 4; ++n)
          *(f32x4*)&X[w * 1024 + n * 256 + xo] = acc[m][n];
      }
      __builtin_amdgcn_s_barrier();          // writes visible
      if (s == 1) {
#pragma unroll
        for (int n = 0; n < 4; ++n) {
          const f32x4 g4 = *(const f32x4*)&X[(w - 8) * 1024 + n * 256 + xo];
          const int c  = col0 + n * 16 + lr;
          const int rb = row0 + m * 16 + lg * 4;
#pragma unroll
          for (int j = 0; j < 4; ++j)
            G[(size_t)(rb + j) * N + c] = f2bf(silu(g4[j]) * acc[m][n][j]);
        }
      }
    }
  }
}

extern "C" void kernel_launch(void* const* d_in, const int* in_sizes, int n_in,
                              void* d_out, int out_size, void* d_ws, size_t ws_size,
                              hipStream_t stream) {
  const float* x   = (const float*)d_in[0];
  const float* Wg  = (const float*)d_in[1];
  const float* Wu  = (const float*)d_in[2];
  const float* Wd  = (const float*)d_in[3];
  const int*   top = (const int*)d_in[4];
  const float* wt  = (const float*)d_in[5];
  float* out = (float*)d_out;

  const size_t NE_X = (size_t)NSEL * HIDDEN;
  const size_t NE_W = (size_t)INTER * HIDDEN;
  if (ws_size < (NE_X + 4 * NE_W) * sizeof(uint16_t)) return;

  uint16_t* xs = (uint16_t*)d_ws;
  uint16_t* w1 = xs + NE_X;    // Wg bf16
  uint16_t* w2 = w1 + NE_W;    // Wu bf16
  uint16_t* w3 = w2 + NE_W;    // Wd bf16
  uint16_t* gh = w3 + NE_W;    // h bf16 [NSEL][INTER]

  const int NCVT = (int)(NE_W / 16384);   // 3584 blocks per weight (prep)
  const int NCVT_GU = (int)(NE_W / 65536);// 896 tail blocks (inside GU)
  const int ngGU = 16 * (INTER / 128);    // 1792
  const int ngDN = 16 * (HIDDEN / 256);   // 256

  // gather + Wg,Wu cvts (Wd cvt rides inside the GU launch)
  prep<<<NSEL + 2 * NCVT, 256, 0, stream>>>(x, top, xs, Wg, w1, Wu, w2, NCVT);

  // fused gate+up: h = silu(x Wg^T) * (x Wu^T) -> gh; tail: Wd -> w3
  gemm_f<0><<<ngGU + NCVT_GU, 1024, 0, stream>>>(xs, w1, w2, gh, nullptr, nullptr,
                                                 INTER, HIDDEN, ngGU, Wd, w3);
  // down + routing weight: out = (h Wd^T) * weight[:,None]
  gemm_f<1><<<ngDN, 1024, 0, stream>>>(gh, w3, nullptr, nullptr, out, wt,
                                       HIDDEN, INTER, ngDN, nullptr, nullptr);
}

// Round 15
// 1327.233 us; speedup vs baseline: 15.5788x; 1.0444x over previous
//
#include <hip/hip_runtime.h>
#include <hip/hip_bf16.h>
#include <stdint.h>

#define HIDDEN 4096
#define INTER  14336
#define NSEL   4096

using short8 = __attribute__((ext_vector_type(8))) short;
using f32x4  = __attribute__((ext_vector_type(4))) float;

__device__ __forceinline__ uint16_t f2bf(float f) {
  uint32_t u = __float_as_uint(f);
  uint32_t r = (u + 0x7FFFu + ((u >> 16) & 1u)) >> 16;
  return (uint16_t)r;
}
__device__ __forceinline__ uint32_t pack2(float lo, float hi) {
  return (uint32_t)f2bf(lo) | ((uint32_t)f2bf(hi) << 16);
}

// ---- prep: gather x_sel->bf16 (blocks<NSEL) + cvt Wg,Wu fp32->bf16 ----
__global__ void prep(const float* __restrict__ x, const int* __restrict__ idx,
                     uint16_t* __restrict__ xs,
                     const float* __restrict__ Wg, uint16_t* __restrict__ w1,
                     const float* __restrict__ Wu, uint16_t* __restrict__ w2,
                     int ncvt) {
  const int b = blockIdx.x;
  const int t = threadIdx.x;
  if (b < NSEL) {
    const size_t s = (size_t)idx[b] * HIDDEN + (size_t)t * 16;
    const size_t d = (size_t)b * HIDDEN + (size_t)t * 16;
    const float4* sp = (const float4*)(x + s);
    float4 f0 = sp[0], f1 = sp[1], f2 = sp[2], f3 = sp[3];
    uint4 v0, v1;
    v0.x = pack2(f0.x, f0.y); v0.y = pack2(f0.z, f0.w);
    v0.z = pack2(f1.x, f1.y); v0.w = pack2(f1.z, f1.w);
    v1.x = pack2(f2.x, f2.y); v1.y = pack2(f2.z, f2.w);
    v1.z = pack2(f3.x, f3.y); v1.w = pack2(f3.z, f3.w);
    *(uint4*)(xs + d)     = v0;
    *(uint4*)(xs + d + 8) = v1;
    return;
  }
  int cb = b - NSEL;
  const float* src; uint16_t* dst;
  if (cb < ncvt) { src = Wg; dst = w1; }
  else           { src = Wu; dst = w2; cb -= ncvt; }
#pragma unroll
  for (int k = 0; k < 8; ++k) {
    const size_t i = (size_t)cb * 16384 + (size_t)k * 2048 + (size_t)t * 8;
    float4 a = *(const float4*)(src + i);
    float4 c = *(const float4*)(src + i + 4);
    uint4 v;
    v.x = pack2(a.x, a.y); v.y = pack2(a.z, a.w);
    v.z = pack2(c.x, c.y); v.w = pack2(c.z, c.w);
    *(uint4*)(dst + i) = v;
  }
}

__device__ __forceinline__ void gload16(const void* g, void* l) {
  __builtin_amdgcn_global_load_lds(
      (const __attribute__((address_space(1))) void*)g,
      (__attribute__((address_space(3))) void*)l, 16, 0, 0);
}

__device__ __forceinline__ float silu(float g) {
  return g / (1.f + __expf(-g));
}

// ============================================================================
// Fused NT GEMM — BK=64 / ring-2 variant of the r13 structure.
// r14 LESSON (race, absmax 6.6e-2): vmcnt is PER-WAVE; a slot staged by all
// waves is readable only after each wave's own vmcnt + a BARRIER. Counted
// multi-subtile schemes need prefetch distance >= 2 barriers -> ring-6 ->
// 192 KB > 160 KB LDS. The fit-legal convoy cut is BK=64 + ring-2 (128 KB):
// ONE vmcnt(0)+barrier per K64 tile (64 barriers vs r13's 128). The drain is
// ~free: tile t+1's loads are issued at the TOP of iteration t, a full
// iteration (~2.5k cyc >> 900-cyc HBM latency) before the drain.
// 1024 threads = 16 waves of 64x64 (acc 64 AGPR + ~56 VGPR -> 16 waves/CU;
// r12 proved deeper occupancy impossible with a 64-reg accumulator).
// Per K64 iteration: {STAGE t+1 (4 gload16/thread) -> ds_read ks0 (8 b128)
// -> 16 MFMA -> ds_read ks1 -> 16 MFMA -> vmcnt(0) -> s_barrier}.
// LDS layout (r8-validated ZERO-conflict A-style for BK=64): panel row =
// 64 u16 = 128B line of 8 16B-slots; slot' = (ks*4+lg) ^ (r&7); ks=1 offset
// = ks=0 offset ^ 32 (u16). Staged via inverse-swizzled global source +
// LINEAR gload_lds dest (rule 21).
// MODE 0 (gate+up): BM=256, BNout=128, TWO B panels (Wg,Wu 128 rows);
//   wave (s=w>>3, wm=w&3, wn=(w>>2)&1); epilogue g/u exchange via LDS
//   (bank-spread perm), h = silu(g)*u -> bf16 G. Tail blocks convert Wd.
// MODE 1 (down): BM=256, BN=256 single panel; out = acc*Wt[row], NT store.
// T1 bijective XCD swizzle over the gemm sub-grid, bm-fastest. T5 setprio.
// ============================================================================
template<int MODE>
__global__ __launch_bounds__(1024, 4) void gemm_f(
    const uint16_t* __restrict__ A,
    const uint16_t* __restrict__ B0,
    const uint16_t* __restrict__ B1,
    uint16_t* __restrict__ G,
    float* __restrict__ O,
    const float* __restrict__ Wt,
    int N, int K, int nGemm,
    const float* __restrict__ cvtIn, uint16_t* __restrict__ cvtOut)
{
  __shared__ __align__(16) uint16_t lds[2][32768];  // [buf][A 0..16383 | B 16384..32767]

  const int bid = (int)blockIdx.x;
  const int tid = (int)threadIdx.x;

  // ---- Wd-cvt tail (MODE 0 only): 65536 elems/block, 64/thread ----
  if (MODE == 0 && bid >= nGemm) {
    const int cb = bid - nGemm;
#pragma unroll
    for (int k = 0; k < 8; ++k) {
      const size_t i = (size_t)cb * 65536 + (size_t)k * 8192 + (size_t)tid * 8;
      float4 a = *(const float4*)(cvtIn + i);
      float4 c = *(const float4*)(cvtIn + i + 4);
      uint4 v;
      v.x = pack2(a.x, a.y); v.y = pack2(a.z, a.w);
      v.z = pack2(c.x, c.y); v.w = pack2(c.z, c.w);
      *(uint4*)(cvtOut + i) = v;
    }
    return;
  }

  const int lid = (bid & 7) * (nGemm >> 3) + (bid >> 3);
  const int bm = lid & 15, bn = lid >> 4;           // nbm = 16 always

  const int lane = tid & 63, w = tid >> 6;
  const int lr = lane & 15, lg = lane >> 4;

  int wm, wn, s;
  if constexpr (MODE == 0) { s = w >> 3; wm = w & 3; wn = (w >> 2) & 1; }
  else                     { s = 0;      wm = w & 3; wn = w >> 2;       }

  // ---- fragment read offsets (u16, buf-relative), ks=0; ks=1 = ^32 ----
  // row r = 128B line; slot = lg ^ (r&7)  [r8-validated zero-conflict]
  int offA[4], offB[4];
#pragma unroll
  for (int m = 0; m < 4; ++m) {
    const int r = wm * 64 + m * 16 + lr;
    offA[m] = r * 64 + ((lg ^ (r & 7)) * 8);
  }
  const int bBase = (MODE == 0) ? (16384 + s * 8192) : 16384;
#pragma unroll
  for (int n = 0; n < 4; ++n) {
    const int r = wn * 64 + n * 16 + lr;
    offB[n] = bBase + r * 64 + ((lg ^ (r & 7)) * 8);
  }

  // ---- staging (inverse-swizzled global source, linear gload_lds dest) ----
  // A: 256 rows x 64 cols = 2048 chunks; thread covers rows tid>>3, +128.
  const int rA = tid >> 3;
  const int sA = (tid & 7) ^ (rA & 7);
  const uint16_t* aSrc = A + (size_t)(bm * 256 + rA) * K + sA * 8;
  // B: MODE0 = two 128-row panels (tid<512 -> Wg, else Wu), rows jB>>3, +64.
  //    MODE1 = one 256-row panel, rows tid>>3, +128.
  const int jB = (MODE == 0) ? (tid & 511) : tid;
  const int rB = jB >> 3;
  const int sB = (jB & 7) ^ (rB & 7);
  const uint16_t* bSel = (MODE == 0) ? ((tid < 512) ? B0 : B1) : B0;
  const uint16_t* bSrc = bSel + (size_t)(bn * ((MODE == 0) ? 128 : 256) + rB) * K + sB * 8;
  const int bRowStep = (MODE == 0) ? 64 : 128;          // rows to 2nd B chunk
  const int bDst0 = (MODE == 0) ? (16384 + (tid >> 9) * 8192 + jB * 8)
                                : (16384 + tid * 8);
  const int bDst1 = bDst0 + ((MODE == 0) ? 4096 : 8192);

#define STAGE(tt, q) do { \
    const size_t ko = (size_t)(tt) * 64; \
    gload16(aSrc + ko,                      &lds[q][tid * 8]); \
    gload16(aSrc + (size_t)128 * K + ko,    &lds[q][8192 + tid * 8]); \
    gload16(bSrc + ko,                      &lds[q][bDst0]); \
    gload16(bSrc + (size_t)bRowStep * K + ko, &lds[q][bDst1]); \
  } while (0)

  f32x4 acc[4][4];
#pragma unroll
  for (int m = 0; m < 4; ++m)
#pragma unroll
    for (int n = 0; n < 4; ++n)
#pragma unroll
      for (int j = 0; j < 4; ++j) acc[m][n][j] = 0.f;

  const int nt = K >> 6;   // K64 tiles: GU 64, down 224

  // prologue: stage tile 0, full drain, barrier (globally certified)
  STAGE(0, 0);
  asm volatile("s_waitcnt vmcnt(0)" ::: "memory");
  __builtin_amdgcn_s_barrier();

  for (int t = 0; t < nt; ++t) {
    const uint16_t* S = &lds[t & 1][0];

    // issue next tile's loads FIRST: a full iteration to land before drain
    if (t + 1 < nt) STAGE(t + 1, (t + 1) & 1);

    short8 av[4], bv[4];
    // ---- ks = 0 ----
#pragma unroll
    for (int m = 0; m < 4; ++m) av[m] = *(const short8*)&S[offA[m]];
#pragma unroll
    for (int n = 0; n < 4; ++n) bv[n] = *(const short8*)&S[offB[n]];
    __builtin_amdgcn_s_setprio(1);
#pragma unroll
    for (int m = 0; m < 4; ++m)
#pragma unroll
      for (int n = 0; n < 4; ++n)
        acc[m][n] = __builtin_amdgcn_mfma_f32_16x16x32_bf16(av[m], bv[n], acc[m][n], 0, 0, 0);
    __builtin_amdgcn_s_setprio(0);

    // ---- ks = 1 (offset ^32: slot bit 2) ----
#pragma unroll
    for (int m = 0; m < 4; ++m) av[m] = *(const short8*)&S[offA[m] ^ 32];
#pragma unroll
    for (int n = 0; n < 4; ++n) bv[n] = *(const short8*)&S[offB[n] ^ 32];
    __builtin_amdgcn_s_setprio(1);
#pragma unroll
    for (int m = 0; m < 4; ++m)
#pragma unroll
      for (int n = 0; n < 4; ++n)
        acc[m][n] = __builtin_amdgcn_mfma_f32_16x16x32_bf16(av[m], bv[n], acc[m][n], 0, 0, 0);
    __builtin_amdgcn_s_setprio(0);

    // full drain + barrier: globally certifies tile t+1 (race-free by
    // construction — r14's counted mid-iteration scheme was NOT)
    asm volatile("s_waitcnt vmcnt(0)" ::: "memory");
    __builtin_amdgcn_s_barrier();
  }
#undef STAGE

  // C/D layout: col = lane&15, row = (lane>>4)*4 + reg  [m89-verified]
  if constexpr (MODE == 1) {
    const int row0 = bm * 256 + wm * 64, col0 = bn * 256 + wn * 64;
#pragma unroll
    for (int m = 0; m < 4; ++m)
#pragma unroll
      for (int n = 0; n < 4; ++n) {
        const int c  = col0 + n * 16 + lr;
        const int rb = row0 + m * 16 + lg * 4;
#pragma unroll
        for (int j = 0; j < 4; ++j) {
          const int r = rb + j;
          __builtin_nontemporal_store(acc[m][n][j] * Wt[r], &O[(size_t)r * N + c]);
        }
      }
  } else {
    // g/u exchange via LDS; bank-spread perm (2-way max = free)
    float* X = (float*)&lds[0][0];   // 8 g-waves x 4KB = 32KB (loop-dead)
    const int xo = lr * 16 + ((lg ^ ((lr >> 1) & 3)) * 4);
    const int row0 = bm * 256 + wm * 64, col0 = bn * 128 + wn * 64;
#pragma unroll
    for (int m = 0; m < 4; ++m) {
      __builtin_amdgcn_s_barrier();          // prev phase's reads done
      if (s == 0) {
#pragma unroll
        for (int n = 0; n < 4; ++n)
          *(f32x4*)&X[w * 1024 + n * 256 + xo] = acc[m][n];
      }
      __builtin_amdgcn_s_barrier();          // writes visible
      if (s == 1) {
#pragma unroll
        for (int n = 0; n < 4; ++n) {
          const f32x4 g4 = *(const f32x4*)&X[(w - 8) * 1024 + n * 256 + xo];
          const int c  = col0 + n * 16 + lr;
          const int rb = row0 + m * 16 + lg * 4;
#pragma unroll
          for (int j = 0; j < 4; ++j)
            G[(size_t)(rb + j) * N + c] = f2bf(silu(g4[j]) * acc[m][n][j]);
        }
      }
    }
  }
}

extern "C" void kernel_launch(void* const* d_in, const int* in_sizes, int n_in,
                              void* d_out, int out_size, void* d_ws, size_t ws_size,
                              hipStream_t stream) {
  const float* x   = (const float*)d_in[0];
  const float* Wg  = (const float*)d_in[1];
  const float* Wu  = (const float*)d_in[2];
  const float* Wd  = (const float*)d_in[3];
  const int*   top = (const int*)d_in[4];
  const float* wt  = (const float*)d_in[5];
  float* out = (float*)d_out;

  const size_t NE_X = (size_t)NSEL * HIDDEN;
  const size_t NE_W = (size_t)INTER * HIDDEN;
  if (ws_size < (NE_X + 4 * NE_W) * sizeof(uint16_t)) return;

  uint16_t* xs = (uint16_t*)d_ws;
  uint16_t* w1 = xs + NE_X;    // Wg bf16
  uint16_t* w2 = w1 + NE_W;    // Wu bf16
  uint16_t* w3 = w2 + NE_W;    // Wd bf16
  uint16_t* gh = w3 + NE_W;    // h bf16 [NSEL][INTER]

  const int NCVT = (int)(NE_W / 16384);   // 3584 blocks per weight (prep)
  const int NCVT_GU = (int)(NE_W / 65536);// 896 tail blocks (inside GU)
  const int ngGU = 16 * (INTER / 128);    // 1792
  const int ngDN = 16 * (HIDDEN / 256);   // 256

  // gather + Wg,Wu cvts (Wd cvt rides inside the GU launch)
  prep<<<NSEL + 2 * NCVT, 256, 0, stream>>>(x, top, xs, Wg, w1, Wu, w2, NCVT);

  // fused gate+up: h = silu(x Wg^T) * (x Wu^T) -> gh; tail: Wd -> w3
  gemm_f<0><<<ngGU + NCVT_GU, 1024, 0, stream>>>(xs, w1, w2, gh, nullptr, nullptr,
                                                 INTER, HIDDEN, ngGU, Wd, w3);
  // down + routing weight: out = (h Wd^T) * weight[:,None]
  gemm_f<1><<<ngDN, 1024, 0, stream>>>(gh, w3, nullptr, nullptr, out, wt,
                                       HIDDEN, INTER, ngDN, nullptr, nullptr);
}

// Round 17
// 1307.177 us; speedup vs baseline: 15.8178x; 1.0153x over previous
//
#include <hip/hip_runtime.h>
#include <hip/hip_bf16.h>
#include <stdint.h>

#define HIDDEN 4096
#define INTER  14336
#define NSEL   4096

using short8 = __attribute__((ext_vector_type(8))) short;
using f32x4  = __attribute__((ext_vector_type(4))) float;
using u32x4  = __attribute__((ext_vector_type(4))) unsigned int;

__device__ __forceinline__ uint16_t f2bf(float f) {
  uint32_t u = __float_as_uint(f);
  uint32_t r = (u + 0x7FFFu + ((u >> 16) & 1u)) >> 16;
  return (uint16_t)r;
}
__device__ __forceinline__ uint32_t pack2(float lo, float hi) {
  return (uint32_t)f2bf(lo) | ((uint32_t)f2bf(hi) << 16);
}

// NT fp32x4 load via native vector type (__builtin_nontemporal_load rejects
// HIP_vector_type structs — r16 compile lesson).
__device__ __forceinline__ f32x4 ntload4(const float* p) {
  return __builtin_nontemporal_load((const f32x4*)p);
}
__device__ __forceinline__ u32x4 cvt8(f32x4 a, f32x4 c) {
  u32x4 v;
  v[0] = pack2(a[0], a[1]); v[1] = pack2(a[2], a[3]);
  v[2] = pack2(c[0], c[1]); v[3] = pack2(c[2], c[3]);
  return v;
}

// ---- prep: gather x_sel->bf16 (blocks<NSEL) + cvt Wg,Wu fp32->bf16 ----
// fp32 weight reads are NON-TEMPORAL: read-once streams must not allocate
// in L3 (they evict the bf16 panels the GEMMs need resident).
__global__ void prep(const float* __restrict__ x, const int* __restrict__ idx,
                     uint16_t* __restrict__ xs,
                     const float* __restrict__ Wg, uint16_t* __restrict__ w1,
                     const float* __restrict__ Wu, uint16_t* __restrict__ w2,
                     int ncvt) {
  const int b = blockIdx.x;
  const int t = threadIdx.x;
  if (b < NSEL) {
    const size_t s = (size_t)idx[b] * HIDDEN + (size_t)t * 16;
    const size_t d = (size_t)b * HIDDEN + (size_t)t * 16;
    f32x4 f0 = *(const f32x4*)(x + s);
    f32x4 f1 = *(const f32x4*)(x + s + 4);
    f32x4 f2 = *(const f32x4*)(x + s + 8);
    f32x4 f3 = *(const f32x4*)(x + s + 12);
    *(u32x4*)(xs + d)     = cvt8(f0, f1);
    *(u32x4*)(xs + d + 8) = cvt8(f2, f3);
    return;
  }
  int cb = b - NSEL;
  const float* src; uint16_t* dst;
  if (cb < ncvt) { src = Wg; dst = w1; }
  else           { src = Wu; dst = w2; cb -= ncvt; }
#pragma unroll
  for (int k = 0; k < 8; ++k) {
    const size_t i = (size_t)cb * 16384 + (size_t)k * 2048 + (size_t)t * 8;
    f32x4 a = ntload4(src + i);
    f32x4 c = ntload4(src + i + 4);
    *(u32x4*)(dst + i) = cvt8(a, c);
  }
}

__device__ __forceinline__ void gload16(const void* g, void* l) {
  __builtin_amdgcn_global_load_lds(
      (const __attribute__((address_space(1))) void*)g,
      (__attribute__((address_space(3))) void*)l, 16, 0, 0);
}

__device__ __forceinline__ float silu(float g) {
  return g / (1.f + __expf(-g));
}

// ============================================================================
// Fused NT GEMM — r15 structure (measured best: 1327 µs), + NON-TEMPORAL
// fp32 reads in the Wd-cvt tail. r15 forensics: GU FETCH = 1.15 GB vs a
// ~735 MB unique read set — the tail's 469 MB fp32 stream allocates in L3
// and evicts the GEMM's A/B panels mid-flight, forcing HBM refetch (~400 MB)
// and supply stalls (GU ~4.4k cyc/tile vs down-GEMM's ~3.2k, same code).
// NT loads keep the read-once stream out of L3; bf16 writes stay normal
// (w3 is re-read by the down GEMM and should be L3-resident).
// --- r15 structure recap ---
// BK=64 / ring-2 (128 KB), ONE vmcnt(0)+barrier per K64 (drain ~free: next
// tile's loads issued a full iteration earlier). vmcnt is PER-WAVE: slot
// readable only after own-vmcnt + barrier (r14 race lesson).
// 1024 threads = 16 waves of 64x64 (acc 64 AGPR + ~60 VGPR -> 16 waves/CU;
// r12 proved deeper occupancy impossible with a 64-reg accumulator).
// Per K64 iteration: {STAGE t+1 (4 gload16/thread) -> ds_read ks0 (8 b128)
// -> 16 MFMA -> ds_read ks1 -> 16 MFMA -> vmcnt(0) -> s_barrier}.
// LDS layout (zero-conflict, r8/r15-validated): panel row = 128B line of 8
// 16B-slots; slot' = (ks*4+lg) ^ (r&7); ks1 offset = ks0 ^ 32 (u16).
// Inverse-swizzled global source + LINEAR gload_lds dest (rule 21).
// MODE 0 (gate+up): BM=256, BNout=128, TWO B panels (Wg,Wu 128 rows);
//   wave (s=w>>3, wm=w&3, wn=(w>>2)&1); epilogue g/u exchange via LDS
//   (bank-spread perm), h = silu(g)*u -> bf16 G. Tail blocks convert Wd.
// MODE 1 (down): BM=256, BN=256 single panel; out = acc*Wt[row], NT store.
// T1 bijective XCD swizzle over the gemm sub-grid, bm-fastest. T5 setprio.
// ============================================================================
template<int MODE>
__global__ __launch_bounds__(1024, 4) void gemm_f(
    const uint16_t* __restrict__ A,
    const uint16_t* __restrict__ B0,
    const uint16_t* __restrict__ B1,
    uint16_t* __restrict__ G,
    float* __restrict__ O,
    const float* __restrict__ Wt,
    int N, int K, int nGemm,
    const float* __restrict__ cvtIn, uint16_t* __restrict__ cvtOut)
{
  __shared__ __align__(16) uint16_t lds[2][32768];  // [buf][A 0..16383 | B 16384..32767]

  const int bid = (int)blockIdx.x;
  const int tid = (int)threadIdx.x;

  // ---- Wd-cvt tail (MODE 0 only): 65536 elems/block, NT fp32 reads ----
  if (MODE == 0 && bid >= nGemm) {
    const int cb = bid - nGemm;
#pragma unroll
    for (int k = 0; k < 8; ++k) {
      const size_t i = (size_t)cb * 65536 + (size_t)k * 8192 + (size_t)tid * 8;
      f32x4 a = ntload4(cvtIn + i);
      f32x4 c = ntload4(cvtIn + i + 4);
      *(u32x4*)(cvtOut + i) = cvt8(a, c);
    }
    return;
  }

  const int lid = (bid & 7) * (nGemm >> 3) + (bid >> 3);
  const int bm = lid & 15, bn = lid >> 4;           // nbm = 16 always

  const int lane = tid & 63, w = tid >> 6;
  const int lr = lane & 15, lg = lane >> 4;

  int wm, wn, s;
  if constexpr (MODE == 0) { s = w >> 3; wm = w & 3; wn = (w >> 2) & 1; }
  else                     { s = 0;      wm = w & 3; wn = w >> 2;       }

  // ---- fragment read offsets (u16, buf-relative), ks=0; ks=1 = ^32 ----
  int offA[4], offB[4];
#pragma unroll
  for (int m = 0; m < 4; ++m) {
    const int r = wm * 64 + m * 16 + lr;
    offA[m] = r * 64 + ((lg ^ (r & 7)) * 8);
  }
  const int bBase = (MODE == 0) ? (16384 + s * 8192) : 16384;
#pragma unroll
  for (int n = 0; n < 4; ++n) {
    const int r = wn * 64 + n * 16 + lr;
    offB[n] = bBase + r * 64 + ((lg ^ (r & 7)) * 8);
  }

  // ---- staging (inverse-swizzled global source, linear gload_lds dest) ----
  const int rA = tid >> 3;
  const int sA = (tid & 7) ^ (rA & 7);
  const uint16_t* aSrc = A + (size_t)(bm * 256 + rA) * K + sA * 8;
  const int jB = (MODE == 0) ? (tid & 511) : tid;
  const int rB = jB >> 3;
  const int sB = (jB & 7) ^ (rB & 7);
  const uint16_t* bSel = (MODE == 0) ? ((tid < 512) ? B0 : B1) : B0;
  const uint16_t* bSrc = bSel + (size_t)(bn * ((MODE == 0) ? 128 : 256) + rB) * K + sB * 8;
  const int bRowStep = (MODE == 0) ? 64 : 128;
  const int bDst0 = (MODE == 0) ? (16384 + (tid >> 9) * 8192 + jB * 8)
                                : (16384 + tid * 8);
  const int bDst1 = bDst0 + ((MODE == 0) ? 4096 : 8192);

#define STAGE(tt, q) do { \
    const size_t ko = (size_t)(tt) * 64; \
    gload16(aSrc + ko,                      &lds[q][tid * 8]); \
    gload16(aSrc + (size_t)128 * K + ko,    &lds[q][8192 + tid * 8]); \
    gload16(bSrc + ko,                      &lds[q][bDst0]); \
    gload16(bSrc + (size_t)bRowStep * K + ko, &lds[q][bDst1]); \
  } while (0)

  f32x4 acc[4][4];
#pragma unroll
  for (int m = 0; m < 4; ++m)
#pragma unroll
    for (int n = 0; n < 4; ++n)
#pragma unroll
      for (int j = 0; j < 4; ++j) acc[m][n][j] = 0.f;

  const int nt = K >> 6;   // K64 tiles: GU 64, down 224

  // prologue: stage tile 0, full drain, barrier (globally certified)
  STAGE(0, 0);
  asm volatile("s_waitcnt vmcnt(0)" ::: "memory");
  __builtin_amdgcn_s_barrier();

  for (int t = 0; t < nt; ++t) {
    const uint16_t* S = &lds[t & 1][0];

    // issue next tile's loads FIRST: a full iteration to land before drain
    if (t + 1 < nt) STAGE(t + 1, (t + 1) & 1);

    short8 av[4], bv[4];
    // ---- ks = 0 ----
#pragma unroll
    for (int m = 0; m < 4; ++m) av[m] = *(const short8*)&S[offA[m]];
#pragma unroll
    for (int n = 0; n < 4; ++n) bv[n] = *(const short8*)&S[offB[n]];
    __builtin_amdgcn_s_setprio(1);
#pragma unroll
    for (int m = 0; m < 4; ++m)
#pragma unroll
      for (int n = 0; n < 4; ++n)
        acc[m][n] = __builtin_amdgcn_mfma_f32_16x16x32_bf16(av[m], bv[n], acc[m][n], 0, 0, 0);
    __builtin_amdgcn_s_setprio(0);

    // ---- ks = 1 (offset ^32: slot bit 2) ----
#pragma unroll
    for (int m = 0; m < 4; ++m) av[m] = *(const short8*)&S[offA[m] ^ 32];
#pragma unroll
    for (int n = 0; n < 4; ++n) bv[n] = *(const short8*)&S[offB[n] ^ 32];
    __builtin_amdgcn_s_setprio(1);
#pragma unroll
    for (int m = 0; m < 4; ++m)
#pragma unroll
      for (int n = 0; n < 4; ++n)
        acc[m][n] = __builtin_amdgcn_mfma_f32_16x16x32_bf16(av[m], bv[n], acc[m][n], 0, 0, 0);
    __builtin_amdgcn_s_setprio(0);

    // full drain + barrier: globally certifies tile t+1 (race-free;
    // per-wave vmcnt + barrier is the only legal certification — r14)
    asm volatile("s_waitcnt vmcnt(0)" ::: "memory");
    __builtin_amdgcn_s_barrier();
  }
#undef STAGE

  // C/D layout: col = lane&15, row = (lane>>4)*4 + reg  [m89-verified]
  if constexpr (MODE == 1) {
    const int row0 = bm * 256 + wm * 64, col0 = bn * 256 + wn * 64;
#pragma unroll
    for (int m = 0; m < 4; ++m)
#pragma unroll
      for (int n = 0; n < 4; ++n) {
        const int c  = col0 + n * 16 + lr;
        const int rb = row0 + m * 16 + lg * 4;
#pragma unroll
        for (int j = 0; j < 4; ++j) {
          const int r = rb + j;
          __builtin_nontemporal_store(acc[m][n][j] * Wt[r], &O[(size_t)r * N + c]);
        }
      }
  } else {
    // g/u exchange via LDS; bank-spread perm (2-way max = free)
    float* X = (float*)&lds[0][0];   // 8 g-waves x 4KB = 32KB (loop-dead)
    const int xo = lr * 16 + ((lg ^ ((lr >> 1) & 3)) * 4);
    const int row0 = bm * 256 + wm * 64, col0 = bn * 128 + wn * 64;
#pragma unroll
    for (int m = 0; m < 4; ++m) {
      __builtin_amdgcn_s_barrier();          // prev phase's reads done
      if (s == 0) {
#pragma unroll
        for (int n = 0; n < 4; ++n)
          *(f32x4*)&X[w * 1024 + n * 256 + xo] = acc[m][n];
      }
      __builtin_amdgcn_s_barrier();          // writes visible
      if (s == 1) {
#pragma unroll
        for (int n = 0; n < 4; ++n) {
          const f32x4 g4 = *(const f32x4*)&X[(w - 8) * 1024 + n * 256 + xo];
          const int c  = col0 + n * 16 + lr;
          const int rb = row0 + m * 16 + lg * 4;
#pragma unroll
          for (int j = 0; j < 4; ++j)
            G[(size_t)(rb + j) * N + c] = f2bf(silu(g4[j]) * acc[m][n][j]);
        }
      }
    }
  }
}

extern "C" void kernel_launch(void* const* d_in, const int* in_sizes, int n_in,
                              void* d_out, int out_size, void* d_ws, size_t ws_size,
                              hipStream_t stream) {
  const float* x   = (const float*)d_in[0];
  const float* Wg  = (const float*)d_in[1];
  const float* Wu  = (const float*)d_in[2];
  const float* Wd  = (const float*)d_in[3];
  const int*   top = (const int*)d_in[4];
  const float* wt  = (const float*)d_in[5];
  float* out = (float*)d_out;

  const size_t NE_X = (size_t)NSEL * HIDDEN;
  const size_t NE_W = (size_t)INTER * HIDDEN;
  if (ws_size < (NE_X + 4 * NE_W) * sizeof(uint16_t)) return;

  uint16_t* xs = (uint16_t*)d_ws;
  uint16_t* w1 = xs + NE_X;    // Wg bf16
  uint16_t* w2 = w1 + NE_W;    // Wu bf16
  uint16_t* w3 = w2 + NE_W;    // Wd bf16
  uint16_t* gh = w3 + NE_W;    // h bf16 [NSEL][INTER]

  const int NCVT = (int)(NE_W / 16384);   // 3584 blocks per weight (prep)
  const int NCVT_GU = (int)(NE_W / 65536);// 896 tail blocks (inside GU)
  const int ngGU = 16 * (INTER / 128);    // 1792
  const int ngDN = 16 * (HIDDEN / 256);   // 256

  // gather + Wg,Wu cvts (Wd cvt rides inside the GU launch)
  prep<<<NSEL + 2 * NCVT, 256, 0, stream>>>(x, top, xs, Wg, w1, Wu, w2, NCVT);

  // fused gate+up: h = silu(x Wg^T) * (x Wu^T) -> gh; tail: Wd -> w3
  gemm_f<0><<<ngGU + NCVT_GU, 1024, 0, stream>>>(xs, w1, w2, gh, nullptr, nullptr,
                                                 INTER, HIDDEN, ngGU, Wd, w3);
  // down + routing weight: out = (h Wd^T) * weight[:,None]
  gemm_f<1><<<ngDN, 1024, 0, stream>>>(gh, w3, nullptr, nullptr, out, wt,
                                       HIDDEN, INTER, ngDN, nullptr, nullptr);
}